// Round 8
// baseline (1384.090 us; speedup 1.0000x reference)
//
#include <hip/hip_runtime.h>
#include <hip/hip_fp16.h>
#include <math.h>

#define NNODES 65536
#define NEDGES 1048576
#define NGRAPHS 64

typedef __attribute__((ext_vector_type(8))) _Float16 half8;
typedef __attribute__((ext_vector_type(2))) _Float16 h2v;
typedef __attribute__((ext_vector_type(4))) float f32x4;

// ---- order-preserving float<->uint encoding for atomicMax-based max ----
__device__ __forceinline__ unsigned encf(float f) {
    unsigned u = __float_as_uint(f);
    return (u & 0x80000000u) ? ~u : (u | 0x80000000u);
}
__device__ __forceinline__ float decf(unsigned u) {
    unsigned v = (u & 0x80000000u) ? (u & 0x7FFFFFFFu) : ~u;
    return __uint_as_float(v);
}
#define ENC_NEG_INF 0x007FFFFFu   // encf(-inf)

// CK-style barrier: drains LDS ops only (no vmcnt(0) like __syncthreads),
// so register-destined global loads stay in flight across it.
__device__ __forceinline__ void bar_sync() {
    __asm__ __volatile__("s_waitcnt lgkmcnt(0)\n\ts_barrier" ::: "memory");
}

__device__ __forceinline__ unsigned short f2h(float v) {
    return __half_as_ushort(__float2half(v));
}
__device__ __forceinline__ void storeY(float* p, float v) { *p = v; }
__device__ __forceinline__ void storeY(unsigned short* p, float v) { *p = f2h(v); }

// relu(u+v) on 8 packed f16 (v_pk_add_f16 + v_pk_max_f16)
__device__ __forceinline__ uint4 hpack(uint4 u, uint4 v) {
    union P { uint4 q; h2v h[4]; };
    P U, V, W;
    U.q = u; V.q = v;
    h2v z = (h2v)(_Float16)0.0f;
#pragma unroll
    for (int j = 0; j < 4; j++) {
        h2v s = U.h[j] + V.h[j];
        W.h[j] = __builtin_elementwise_max(s, z);
    }
    return W.q;
}

// ============================ CSR build ============================
__global__ void k_init(int* deg, int* cursor, unsigned* poolEnc) {
    int i = blockIdx.x * 256 + threadIdx.x;
    if (i < NNODES) { deg[i] = 0; cursor[i] = 0; }
    if (i < NGRAPHS * 256) poolEnc[i] = ENC_NEG_INF;
}

__global__ void k_count(const int* __restrict__ ei, int* deg) {
    int e = blockIdx.x * 256 + threadIdx.x;
    atomicAdd(&deg[ei[NEDGES + e]], 1);
}

__global__ void k_scan1(const int* __restrict__ deg, int* rowptr, int* bsum) {
    __shared__ int s[256];
    int t = threadIdx.x, b = blockIdx.x;
    int v = deg[b * 256 + t];
    s[t] = v;
    __syncthreads();
    for (int off = 1; off < 256; off <<= 1) {
        int x = (t >= off) ? s[t - off] : 0;
        __syncthreads();
        if (t >= off) s[t] += x;
        __syncthreads();
    }
    rowptr[b * 256 + t] = s[t] - v;       // local exclusive
    if (t == 255) bsum[b] = s[255];
}

__global__ void k_scan2(const int* __restrict__ bsum, int* boff) {
    __shared__ int s[256];
    int t = threadIdx.x;
    int v = bsum[t];
    s[t] = v;
    __syncthreads();
    for (int off = 1; off < 256; off <<= 1) {
        int x = (t >= off) ? s[t - off] : 0;
        __syncthreads();
        if (t >= off) s[t] += x;
        __syncthreads();
    }
    boff[t] = s[t] - v;                   // exclusive block offsets
}

__global__ void k_scan3(int* rowptr, const int* __restrict__ boff) {
    int i = blockIdx.x * 256 + threadIdx.x;
    rowptr[i] += boff[blockIdx.x];
    if (i == 0) rowptr[NNODES] = NEDGES;
}

__global__ void k_scatter(const int* __restrict__ ei, const int* __restrict__ rowptr,
                          int* cursor, int* csr_src, int* csr_dst) {
    int e = blockIdx.x * 256 + threadIdx.x;
    int s = ei[e], d = ei[NEDGES + e];
    int pos = rowptr[d] + atomicAdd(&cursor[d], 1);
    csr_src[pos] = s;
    csr_dst[pos] = d;
}

// ============== layer-1 U/V precompute (scalar, FIN=3 is trivial) ==============
template <int FIN, int H>
__global__ __launch_bounds__(256) void k_uv(const float* __restrict__ X,
                                            const float* __restrict__ W1,
                                            const float* __restrict__ B1,
                                            unsigned short* __restrict__ Uh,
                                            unsigned short* __restrict__ Vh) {
    constexpr int NPT = (16 * H) / 256;
    __shared__ float xs[16][FIN];
    int tid = threadIdx.x;
    int n0 = blockIdx.x * 16;
    for (int idx = tid; idx < 16 * FIN; idx += 256)
        xs[idx / FIN][idx % FIN] = X[(size_t)(n0 + idx / FIN) * FIN + (idx % FIN)];
    __syncthreads();
    int h = tid & (H - 1);
    int nb = (tid / H) * NPT;
    float u[NPT], v[NPT];
    float bb = B1[h];
#pragma unroll
    for (int n = 0; n < NPT; n++) { u[n] = bb; v[n] = 0.f; }
    for (int f = 0; f < FIN; f++) {
        float wt = W1[f * H + h];
        float wb = W1[(FIN + f) * H + h];
        float wd = wt - wb;
#pragma unroll
        for (int n = 0; n < NPT; n++) {
            float xv = xs[nb + n][f];
            u[n] += xv * wd;
            v[n] += xv * wb;
        }
    }
#pragma unroll
    for (int n = 0; n < NPT; n++) {
        Uh[(size_t)(n0 + nb + n) * H + h] = f2h(u[n]);
        Vh[(size_t)(n0 + nb + n) * H + h] = f2h(v[n]);
    }
}

// ============== layers-2/3 U/V precompute via MFMA (f16) ==============
// [U | V] = X @ [Wd | Wb], Wd = W1_top - W1_bot, Wb = W1_bot. X is f16.
template <int K, int H, int CWAVES>
__global__ __launch_bounds__(CWAVES * 64, 4)
void k_uvm(const unsigned short* __restrict__ Xh,
           const float* __restrict__ W1,
           const float* __restrict__ B1,
           unsigned short* __restrict__ Uh,
           unsigned short* __restrict__ Vh) {
    constexpr int BLOCK = CWAVES * 64;
    constexpr int KP = K + 8;
    constexpr int CPW = (2 * H) / CWAVES;
    constexpr int NT = CPW / 16;
    constexpr int KS = K / 32;
    static_assert(BLOCK == 32 * (K / 8), "X-stage mapping");

    __shared__ unsigned short xs[32 * KP];

    int tid = threadIdx.x;
    int n0 = blockIdx.x * 32;
    int ln = tid & 15;
    int qd = (tid >> 4) & 3;
    int cw = tid >> 6;

    // stage X tile (32 x K f16), padded stride
    {
        int r = tid / (K / 8);
        int ck = (tid % (K / 8)) * 8;
        uint4 w = *(const uint4*)&Xh[(size_t)(n0 + r) * K + ck];
        *(uint4*)&xs[r * KP + ck] = w;
    }

    // B fragments: cols [0,H) = Wd, [H,2H) = Wb
    half8 Bf[NT][KS];
#pragma unroll
    for (int nt = 0; nt < NT; nt++) {
        int col = cw * CPW + nt * 16 + ln;
#pragma unroll
        for (int ks = 0; ks < KS; ks++) {
            int kb = ks * 32 + qd * 8;
            half8 b;
#pragma unroll
            for (int j = 0; j < 8; j++) {
                int k = kb + j;
                float v;
                if (col < H) v = W1[(size_t)k * H + col] - W1[(size_t)(K + k) * H + col];
                else         v = W1[(size_t)(K + k) * H + (col - H)];
                b[j] = (_Float16)v;
            }
            Bf[nt][ks] = b;
        }
    }
    __syncthreads();

    f32x4 acc[2][NT];
#pragma unroll
    for (int mt = 0; mt < 2; mt++)
#pragma unroll
        for (int nt = 0; nt < NT; nt++)
            acc[mt][nt] = (f32x4){0.f, 0.f, 0.f, 0.f};

#pragma unroll
    for (int ks = 0; ks < KS; ks++) {
        int ko = ks * 32 + qd * 8;
        half8 a0 = *(const half8*)&xs[ln * KP + ko];
        half8 a1 = *(const half8*)&xs[(16 + ln) * KP + ko];
#pragma unroll
        for (int nt = 0; nt < NT; nt++) {
            acc[0][nt] = __builtin_amdgcn_mfma_f32_16x16x32_f16(a0, Bf[nt][ks], acc[0][nt], 0, 0, 0);
            acc[1][nt] = __builtin_amdgcn_mfma_f32_16x16x32_f16(a1, Bf[nt][ks], acc[1][nt], 0, 0, 0);
        }
    }

#pragma unroll
    for (int mt = 0; mt < 2; mt++) {
#pragma unroll
        for (int nt = 0; nt < NT; nt++) {
            int col = cw * CPW + nt * 16 + ln;
#pragma unroll
            for (int j = 0; j < 4; j++) {
                int node = n0 + mt * 16 + qd * 4 + j;
                float v = acc[mt][nt][j];
                if (col < H) Uh[(size_t)node * H + col] = f2h(v + B1[col]);
                else         Vh[(size_t)node * H + (col - H)] = f2h(v);
            }
        }
    }
}

// ====== fused edge-GEMM (MFMA f16) + segment-max, DUAL-STREAM + V-PIPELINE ======
// Block owns 32 dst nodes = two independent 16-node streams (contiguous CSR).
// Per phase (one stream's tile): issue idx(i+2) -> U(i) -> V(i+1), then merge the
// OTHER stream's ready tile (MFMA), then consume V(i) held in registers since the
// previous iteration. Issue order keeps the hpack wait at vmcnt(2) so the V
// prefetch stays outstanding across bar_sync (lgkm-only drain).
template <int H, int F, int RWAVES, int CWAVES, int MINW, typename YT>
__global__ __launch_bounds__(RWAVES * CWAVES * 64, MINW)
void k_agg(const unsigned short* __restrict__ Uh,
           const unsigned short* __restrict__ Vh,
           const float* __restrict__ W2,
           const float* __restrict__ B2,
           const int* __restrict__ rowptr,
           const int* __restrict__ csr_src,
           const int* __restrict__ csr_dst,
           YT* __restrict__ Y) {
    constexpr int BLOCK = RWAVES * CWAVES * 64;
    constexpr int TR = 32 * RWAVES;         // edge rows per tile
    constexpr int HP = H + 8;               // padded hs row (f16 units)
    constexpr int CPW = F / CWAVES;         // cols per wave
    constexpr int NT = CPW / 16;
    constexpr int KS = H / 32;
    constexpr int ACCSTR = F + 1;
    constexpr int LPR = H / 8;              // threads per hs row
    constexpr int RPP = BLOCK / LPR;        // rows per construction pass
    static_assert(TR == 2 * RPP, "construction must be exactly 2 passes");

    __shared__ unsigned short hs0[TR * HP], hs1[TR * HP];
    __shared__ unsigned accs[32 * ACCSTR];   // slots 0-15: stream A, 16-31: stream B
    __shared__ signed char slot0[TR], slot1[TR];

    int tid = threadIdx.x;
    int nA = blockIdx.x * 32;                // stream A: [nA, nA+16), B: [nA+16, nA+32)

    int ln = tid & 15;
    int qd = (tid >> 4) & 3;
    int wv = tid >> 6;
    int rw = wv / CWAVES;
    int cw = wv % CWAVES;

    // ---- W2 fragments in registers (f16), once ----
    half8 Bf[NT][KS];
#pragma unroll
    for (int nt = 0; nt < NT; nt++) {
        int col = cw * CPW + nt * 16 + ln;
#pragma unroll
        for (int ks = 0; ks < KS; ks++) {
            int kb = ks * 32 + qd * 8;
            half8 b;
#pragma unroll
            for (int j = 0; j < 8; j++)
                b[j] = (_Float16)W2[(size_t)(kb + j) * F + col];
            Bf[nt][ks] = b;
        }
    }

    for (int idx = tid; idx < 32 * ACCSTR; idx += BLOCK) accs[idx] = ENC_NEG_INF;

    int e0a = rowptr[nA], e1a = rowptr[nA + 16], e1b = rowptr[nA + 32];

    int rid = tid / LPR;            // construction: rows rid and rid+RPP
    int kk = (tid % LPR) * 8;       // 8-elem chunk

    // per-stream pipeline state (all register-resident)
    struct PS {
        int e1, T, b0;               // p0(i) = b0 + i*TR
        uint4 vc0, vc1;              // V data for iter i (in flight since iter i-1)
        int sN0, sN1;                // src idx for iter i+1
        int dC0, dC1;                // dst idx for iter i
        int dN0, dN1;                // dst idx for iter i+1
    };

    auto initPS = [&](PS& P, int e0, int e1) {
        P.e1 = e1;
        P.T = (e1 - e0 + TR - 1) / TR;
        P.b0 = e0 + rid;
        int p0 = P.b0, p1 = p0 + RPP;
        int sC0 = csr_src[p0], sC1 = csr_src[p1];   // OOB-safe: lands in ws
        P.dC0 = csr_dst[p0]; P.dC1 = csr_dst[p1];
        P.sN0 = csr_src[p0 + TR]; P.sN1 = csr_src[p1 + TR];
        P.dN0 = csr_dst[p0 + TR]; P.dN1 = csr_dst[p1 + TR];
        int a0 = (p0 < e1) ? sC0 : 0;
        int a1 = (p1 < e1) ? sC1 : 0;
        P.vc0 = *(const uint4*)&Vh[(size_t)a0 * H + kk];
        P.vc1 = *(const uint4*)&Vh[(size_t)a1 * H + kk];
    };

    auto mfma_merge = [&](const unsigned short* hsX, const signed char* slotX, int slotbase) {
#pragma unroll
        for (int mt = 0; mt < 2; mt++) {
            f32x4 acc[NT];
#pragma unroll
            for (int nt = 0; nt < NT; nt++) acc[nt] = (f32x4){0.f, 0.f, 0.f, 0.f};
#pragma unroll
            for (int ks = 0; ks < KS; ks++) {
                int ko = ks * 32 + qd * 8;
                half8 a = *(const half8*)&hsX[(rw * 32 + mt * 16 + ln) * HP + ko];
#pragma unroll
                for (int nt = 0; nt < NT; nt++)
                    acc[nt] = __builtin_amdgcn_mfma_f32_16x16x32_f16(a, Bf[nt][ks], acc[nt], 0, 0, 0);
            }
            int rbase = rw * 32 + mt * 16 + qd * 4;
            char4 ss = *(const char4*)&slotX[rbase];
#pragma unroll
            for (int nt = 0; nt < NT; nt++) {
                int colw = cw * CPW + nt * 16 + ln;
                float c0 = acc[nt][0], c1 = acc[nt][1], c2 = acc[nt][2], c3 = acc[nt][3];
                float m3 = c3;
                float m2 = (ss.z == ss.w) ? fmaxf(c2, m3) : c2;
                float m1 = (ss.y == ss.z) ? fmaxf(c1, m2) : c1;
                float m0 = (ss.x == ss.y) ? fmaxf(c0, m1) : c0;
                if (ss.x >= 0)                 atomicMax(&accs[(slotbase + (int)ss.x) * ACCSTR + colw], encf(m0));
                if (ss.y >= 0 && ss.y != ss.x) atomicMax(&accs[(slotbase + (int)ss.y) * ACCSTR + colw], encf(m1));
                if (ss.z >= 0 && ss.z != ss.y) atomicMax(&accs[(slotbase + (int)ss.z) * ACCSTR + colw], encf(m2));
                if (ss.w >= 0 && ss.w != ss.z) atomicMax(&accs[(slotbase + (int)ss.w) * ACCSTR + colw], encf(m3));
            }
        }
    };

    // one pipeline phase for stream P at iteration i; merges the other stream's
    // ready tile if doMerge.
    auto phase = [&](PS& P, unsigned short* hsX, signed char* slotX, int nbase,
                     int i, bool doMerge,
                     const unsigned short* hsQ, const signed char* slotQ, int qbase) {
        int p0 = P.b0 + i * TR, p1 = p0 + RPP;
        bool ok0 = p0 < P.e1, ok1 = p1 < P.e1;
        // (1) idx for iter i+2 (raw loads, guarded at use)
        int sF0 = csr_src[p0 + 2 * TR], sF1 = csr_src[p1 + 2 * TR];
        int dF0 = csr_dst[p0 + 2 * TR], dF1 = csr_dst[p1 + 2 * TR];
        // (2) U for iter i (issued BEFORE V so the hpack wait leaves V outstanding)
        int d0 = ok0 ? P.dC0 : 0, d1 = ok1 ? P.dC1 : 0;
        uint4 u0 = *(const uint4*)&Uh[(size_t)d0 * H + kk];
        uint4 u1 = *(const uint4*)&Uh[(size_t)d1 * H + kk];
        // (3) V for iter i+1 (resolves during the NEXT iteration)
        bool on0 = (p0 + TR) < P.e1, on1 = (p1 + TR) < P.e1;
        int a0 = on0 ? P.sN0 : 0, a1 = on1 ? P.sN1 : 0;
        uint4 vn0 = *(const uint4*)&Vh[(size_t)a0 * H + kk];
        uint4 vn1 = *(const uint4*)&Vh[(size_t)a1 * H + kk];

        bool cons = i < P.T;
        // slot bytes from prefetched dst regs (no in-phase global->LDS chain)
        if (cons && kk == 0) {
            slotX[rid]       = ok0 ? (signed char)(P.dC0 - nbase) : -1;
            slotX[rid + RPP] = ok1 ? (signed char)(P.dC1 - nbase) : -1;
        }
        if (doMerge) mfma_merge(hsQ, slotQ, qbase);
        if (cons) {
            uint4 w0 = hpack(u0, P.vc0), w1 = hpack(u1, P.vc1);
            if (!ok0) w0 = (uint4){0u, 0u, 0u, 0u};
            if (!ok1) w1 = (uint4){0u, 0u, 0u, 0u};
            *(uint4*)&hsX[rid * HP + kk] = w0;
            *(uint4*)&hsX[(rid + RPP) * HP + kk] = w1;
        }
        // rotate pipeline registers
        P.vc0 = vn0; P.vc1 = vn1;
        P.dC0 = P.dN0; P.dC1 = P.dN1;
        P.sN0 = sF0; P.sN1 = sF1;
        P.dN0 = dF0; P.dN1 = dF1;
        bar_sync();
    };

    PS A, Bs;
    initPS(A, e0a, e1a);
    initPS(Bs, e1a, e1b);
    bar_sync();   // accs init visible

    int imax = (A.T > Bs.T + 1) ? A.T : (Bs.T + 1);
    for (int i = 0; i < imax; i++) {
        // phase A: construct S0(i), merge S1(i-1)
        phase(A, hs0, slot0, nA, i, (i >= 1) && (i - 1 < Bs.T), hs1, slot1, 16);
        // phase B: construct S1(i), merge S0(i)
        phase(Bs, hs1, slot1, nA + 16, i, (i < A.T), hs0, slot0, 0);
    }

    for (int idx = tid; idx < 32 * F; idx += BLOCK) {
        int sl = idx / F, cc = idx % F;
        float m = decf(accs[sl * ACCSTR + cc]);
        float o = isfinite(m) ? (m + B2[cc]) : 0.f;   // empty segment -> 0
        storeY(&Y[(size_t)(nA + sl) * F + cc], o);
    }
}

// ============================ global max-pool + FC ============================
__global__ void k_pool(const float* __restrict__ X3, const int* __restrict__ batch,
                       unsigned* poolEnc) {
    int gph = blockIdx.x;
    int seg = blockIdx.y;
    int c = threadIdx.x;
    int lo = 0, hi = NNODES;
    while (lo < hi) { int mid = (lo + hi) >> 1; if (batch[mid] < gph) lo = mid + 1; else hi = mid; }
    int start = lo;
    hi = NNODES;
    while (lo < hi) { int mid = (lo + hi) >> 1; if (batch[mid] < gph + 1) lo = mid + 1; else hi = mid; }
    int end = lo;
    int chunk = (end - start + 7) >> 3;
    int s = start + seg * chunk;
    int e = min(end, s + chunk);
    float m = -INFINITY;
    for (int n = s; n < e; n++) m = fmaxf(m, X3[(size_t)n * 256 + c]);
    atomicMax(&poolEnc[gph * 256 + c], encf(m));
}

__global__ __launch_bounds__(128) void k_fc(const unsigned* __restrict__ poolEnc,
                                            const float* __restrict__ Wfc,
                                            const float* __restrict__ Bfc,
                                            float* __restrict__ out) {
    __shared__ float p[256];
    int gph = blockIdx.x, c = threadIdx.x;
    for (int k = c; k < 256; k += 128) {
        float m = decf(poolEnc[gph * 256 + k]);
        p[k] = isfinite(m) ? m : 0.f;
    }
    __syncthreads();
    float s = Bfc[c];
    for (int k = 0; k < 256; k++) s += p[k] * Wfc[k * 128 + c];
    out[gph * 128 + c] = s;
}

// ============================ launch ============================
extern "C" void kernel_launch(void* const* d_in, const int* in_sizes, int n_in,
                              void* d_out, int out_size, void* d_ws, size_t ws_size,
                              hipStream_t stream) {
    const float* x     = (const float*)d_in[0];
    const int*   ei    = (const int*)d_in[1];
    const int*   batch = (const int*)d_in[2];
    const float* w1_1 = (const float*)d_in[3];
    const float* b1_1 = (const float*)d_in[4];
    const float* w2_1 = (const float*)d_in[5];
    const float* b2_1 = (const float*)d_in[6];
    const float* w1_2 = (const float*)d_in[7];
    const float* b1_2 = (const float*)d_in[8];
    const float* w2_2 = (const float*)d_in[9];
    const float* b2_2 = (const float*)d_in[10];
    const float* w1_3 = (const float*)d_in[11];
    const float* b1_3 = (const float*)d_in[12];
    const float* w2_3 = (const float*)d_in[13];
    const float* b2_3 = (const float*)d_in[14];
    const float* wfc  = (const float*)d_in[15];
    const float* bfc  = (const float*)d_in[16];
    float* out = (float*)d_out;

    char* ws = (char*)d_ws;
    size_t off = 0;
    auto alloc = [&](size_t bytes) {
        void* p = ws + off;
        off = (off + bytes + 255) & ~(size_t)255;
        return p;
    };
    int* deg      = (int*)alloc((size_t)NNODES * 4);
    int* cursor   = (int*)alloc((size_t)NNODES * 4);
    int* rowptr   = (int*)alloc((size_t)(NNODES + 1) * 4);
    int* bsum     = (int*)alloc(256 * 4);
    int* boff     = (int*)alloc(256 * 4);
    int* csr_src  = (int*)alloc((size_t)NEDGES * 4);
    int* csr_dst  = (int*)alloc((size_t)NEDGES * 4);
    unsigned short* U = (unsigned short*)alloc((size_t)NNODES * 256 * 2);
    unsigned short* V = (unsigned short*)alloc((size_t)NNODES * 256 * 2);
    unsigned short* x1h = (unsigned short*)alloc((size_t)NNODES * 64 * 2);
    unsigned short* x2h = (unsigned short*)alloc((size_t)NNODES * 128 * 2);
    float* x3     = (float*)alloc((size_t)NNODES * 256 * 4);
    unsigned* poolEnc = (unsigned*)alloc((size_t)NGRAPHS * 256 * 4);
    (void)ws_size; (void)in_sizes; (void)n_in; (void)out_size;

    // CSR by dst (shared across the 3 layers)
    k_init<<<256, 256, 0, stream>>>(deg, cursor, poolEnc);
    k_count<<<NEDGES / 256, 256, 0, stream>>>(ei, deg);
    k_scan1<<<256, 256, 0, stream>>>(deg, rowptr, bsum);
    k_scan2<<<1, 256, 0, stream>>>(bsum, boff);
    k_scan3<<<256, 256, 0, stream>>>(rowptr, boff);
    k_scatter<<<NEDGES / 256, 256, 0, stream>>>(ei, rowptr, cursor, csr_src, csr_dst);

    // layer 1: FIN=3, H=64, F=64  (scalar uv; dual-stream agg 2x2 waves, TR=64)
    k_uv<3, 64><<<NNODES / 16, 256, 0, stream>>>(x, w1_1, b1_1, U, V);
    k_agg<64, 64, 2, 2, 4, unsigned short><<<NNODES / 32, 256, 0, stream>>>(U, V, w2_1, b2_1, rowptr, csr_src, csr_dst, x1h);
    // layer 2: K=64, H=128, F=128 (f16 MFMA uv; dual-stream agg 1x4 waves, TR=32)
    k_uvm<64, 128, 4><<<NNODES / 32, 256, 0, stream>>>(x1h, w1_2, b1_2, U, V);
    k_agg<128, 128, 1, 4, 4, unsigned short><<<NNODES / 32, 256, 0, stream>>>(U, V, w2_2, b2_2, rowptr, csr_src, csr_dst, x2h);
    // layer 3: K=128, H=256, F=256 (f16 MFMA uv; dual-stream agg 1x8 waves, TR=32)
    k_uvm<128, 256, 8><<<NNODES / 32, 512, 0, stream>>>(x2h, w1_3, b1_3, U, V);
    k_agg<256, 256, 1, 8, 4, float><<<NNODES / 32, 512, 0, stream>>>(U, V, w2_3, b2_3, rowptr, csr_src, csr_dst, x3);

    // global max pool + FC
    k_pool<<<dim3(NGRAPHS, 8), 256, 0, stream>>>(x3, batch, poolEnc);
    k_fc<<<NGRAPHS, 128, 0, stream>>>(poolEnc, wfc, bfc, out);
}